// Round 9
// baseline (147.500 us; speedup 1.0000x reference)
//
#include <hip/hip_runtime.h>
#include <hip/hip_bf16.h>

// Causal attention B=2,H=12,S=2048,D=64 fp32 in/out.
// R9 = R8 with the builtin-selection bug fixed: the K=16 MFMA wrapper now
// gates on __HIP_DEVICE_COMPILE__ (host pass has no amdgcn builtins; R8's
// bare __has_builtin fell into a nonexistent fallback name on host).
// Device path uses __builtin_amdgcn_mfma_f32_16x16x16bf16_1k (v4i16 ops).
// Design (from R8): no P LDS round-trip — S^T's C/D layout (lane: q=li,
// kv=g*4+r) IS the K=16 A-operand layout, so exp2(S^T) feeds MFMA directly
// from registers. V B-frags: b64 reads of 4 consecutive kv from transposed
// Vs. Carried: XCD swizzle (3 heads/XCD), double-buffered K/V + 1 barrier/
// iter, bf16 partial O, BM=128, split-K chunks of 8, heavy-first grid,
// static-max base-2 softmax, XOR-swizzled packed LDS.

#define SEQ 2048
#define DH 64
#define NHEADS 24
#define BN 64
#define LDK 72
#define ELEMS_PER_TENSOR (NHEADS * SEQ * DH)          // 3145728
#define NSLOT5 (NHEADS * 16 * 4)                      // 1536
#define WS_BF16  ((size_t)3 * ELEMS_PER_TENSOR * 2)   // 18874368 B
#define WS_FA7   (WS_BF16 + (size_t)NSLOT5 * 8192 * 2 + (size_t)NSLOT5 * 128 * 4)

typedef float f32x4 __attribute__((ext_vector_type(4)));
typedef __bf16 bf16x8 __attribute__((ext_vector_type(8)));
typedef __bf16 bf16x4 __attribute__((ext_vector_type(4)));
typedef short short4v __attribute__((ext_vector_type(4)));

#if __has_builtin(__builtin_amdgcn_exp2f)
#define EXP2F(x) __builtin_amdgcn_exp2f(x)
#else
#define EXP2F(x) exp2f(x)
#endif

#define QSCALE 0.1803368801111204f   // log2(e)/8: folds 1/sqrt(64) + base-2

// K=16 bf16 MFMA. Device pass: the stable gfx90a+ _1k builtin (v4i16 A/B).
// Host pass only semantic-checks this body — give it a stub.
static __device__ __forceinline__ f32x4 mfma16_bf16(bf16x4 a, bf16x4 b, f32x4 c)
{
#if defined(__HIP_DEVICE_COMPILE__)
    short4v as, bs;
    __builtin_memcpy(&as, &a, 8);
    __builtin_memcpy(&bs, &b, 8);
    return __builtin_amdgcn_mfma_f32_16x16x16bf16_1k(as, bs, c, 0, 0, 0);
#else
    (void)a; (void)b;
    return c;
#endif
}

// ---------------- fused pre-pass ----------------
__global__ __launch_bounds__(256)
void prep_kernel(const float* __restrict__ q, const float* __restrict__ k,
                 const float* __restrict__ v,
                 __bf16* __restrict__ qs, __bf16* __restrict__ ks,
                 __bf16* __restrict__ vt)
{
    __shared__ __bf16 T[64][LDK];
    const int bx = blockIdx.x;
    const int tid = threadIdx.x;
    if (bx < 3072) {                       // Q/K bf16 convert
        const int t = bx * 256 + tid;
        const int half = ELEMS_PER_TENSOR / 8;
        const bool is_q = t < half;
        const int idx = (is_q ? t : t - half) * 8;
        const float* src = is_q ? q : k;
        const float sc = is_q ? QSCALE : 1.0f;
        f32x4 a = *(const f32x4*)(src + idx);
        f32x4 b = *(const f32x4*)(src + idx + 4);
        bf16x8 o;
        #pragma unroll
        for (int j = 0; j < 4; ++j) { o[j] = (__bf16)(a[j] * sc); o[4 + j] = (__bf16)(b[j] * sc); }
        *(bf16x8*)((is_q ? qs : ks) + idx) = o;
    } else {                               // V transpose to [bh][d][s]
        const int b2 = bx - 3072;
        const int bh = b2 >> 5;
        const int s0 = (b2 & 31) * 64;
        const int r = tid >> 2, c0 = (tid & 3) * 16;
        const float* vp = v + (size_t)bh * SEQ * DH + (size_t)(s0 + r) * DH + c0;
        __bf16 tmp[16];
        #pragma unroll
        for (int jj = 0; jj < 16; ++jj) tmp[jj] = (__bf16)vp[jj];
        *(bf16x8*)&T[r][c0]     = *(bf16x8*)&tmp[0];
        *(bf16x8*)&T[r][c0 + 8] = *(bf16x8*)&tmp[8];
        __syncthreads();
        const int d = tid >> 2, j0 = (tid & 3) * 16;
        __bf16 o[16];
        #pragma unroll
        for (int jj = 0; jj < 16; ++jj) o[jj] = T[j0 + jj][d];
        __bf16* op = vt + (size_t)bh * DH * SEQ + (size_t)d * SEQ + s0 + j0;
        *(bf16x8*)op       = *(bf16x8*)&o[0];
        *(bf16x8*)(op + 8) = *(bf16x8*)&o[8];
    }
}

// ---------------- main: BM=128, split-K, dbuf, register P ----------------
__global__ __launch_bounds__(256, 4)
void fa8_kernel(const __bf16* __restrict__ qs, const __bf16* __restrict__ ks,
                const __bf16* __restrict__ vt,
                __bf16* __restrict__ opart, float* __restrict__ lpart)
{
    const int bx = blockIdx.x;             // 960 = 8 XCDs x 3 heads x 40
    const int xcd = bx & 7;
    const int sub = bx >> 3;               // 0..119
    const int bh = (sub / 40) * 8 + xcd;   // 3 heads pinned per XCD
    const int rem = 39 - (sub % 40);       // heavy-first within XCD
    int mt2, st;
    if      (rem >= 36) { mt2 = 15; st = 36; }
    else if (rem >= 32) { mt2 = 14; st = 32; }
    else if (rem >= 28) { mt2 = 13; st = 28; }
    else if (rem >= 24) { mt2 = 12; st = 24; }
    else if (rem >= 21) { mt2 = 11; st = 21; }
    else if (rem >= 18) { mt2 = 10; st = 18; }
    else if (rem >= 15) { mt2 = 9;  st = 15; }
    else if (rem >= 12) { mt2 = 8;  st = 12; }
    else if (rem >= 10) { mt2 = 7;  st = 10; }
    else if (rem >= 8)  { mt2 = 6;  st = 8; }
    else if (rem >= 6)  { mt2 = 5;  st = 6; }
    else if (rem >= 4)  { mt2 = 4;  st = 4; }
    else                { mt2 = rem; st = rem; }
    const int chunk = rem - st;
    const int jt0 = chunk * 8;
    const int jt_end = min(jt0 + 8, 2 * mt2 + 2);
    const int q0 = mt2 * 128;

    const int tid = threadIdx.x;
    const int w = tid >> 6, lane = tid & 63;
    const int g = lane >> 4, li = lane & 15;

    __shared__ __bf16 Ks[2][64 * 64];      // 16 KB double-buffered
    __shared__ __bf16 Vs[2][64 * 64];      // 16 KB

    const __bf16* qh = qs + (size_t)bh * SEQ * DH;
    const __bf16* kh = ks + (size_t)bh * SEQ * DH;
    const __bf16* vh = vt + (size_t)bh * DH * SEQ;   // [d][s]

    // Q fragments (B-operand layout for S^T)
    bf16x8 qf[2][2];
    #pragma unroll
    for (int a = 0; a < 2; ++a) {
        const __bf16* qp = qh + (size_t)(q0 + w * 32 + a * 16 + li) * DH + g * 8;
        qf[a][0] = *(const bf16x8*)qp;
        qf[a][1] = *(const bf16x8*)(qp + 32);
    }

    bf16x4 ones4;
    #pragma unroll
    for (int j = 0; j < 4; ++j) ones4[j] = (__bf16)1.0f;

    f32x4 acc[2][4] = {};
    f32x4 accl[2] = {};

    const int srow0 = tid >> 3;            // staging: + s*32
    const int sg    = tid & 7;

    bf16x8 kr[2], vr[2];
    // ---- prologue: tile jt0 -> buf0; issue loads for jt0+1 ----
    #pragma unroll
    for (int s = 0; s < 2; ++s) {
        const int row = s * 32 + srow0;
        const int lg = sg ^ (row & 7);
        kr[s] = *(const bf16x8*)(kh + (size_t)(jt0 * BN + row) * DH + lg * 8);
        vr[s] = *(const bf16x8*)(vh + (size_t)row * SEQ + jt0 * BN + lg * 8);
    }
    #pragma unroll
    for (int s = 0; s < 2; ++s) {
        *(bf16x8*)((char*)Ks[0] + s * 4096 + tid * 16) = kr[s];
        *(bf16x8*)((char*)Vs[0] + s * 4096 + tid * 16) = vr[s];
    }
    if (jt0 + 1 < jt_end) {
        const int kv1 = (jt0 + 1) * BN;
        #pragma unroll
        for (int s = 0; s < 2; ++s) {
            const int row = s * 32 + srow0;
            const int lg = sg ^ (row & 7);
            kr[s] = *(const bf16x8*)(kh + (size_t)(kv1 + row) * DH + lg * 8);
            vr[s] = *(const bf16x8*)(vh + (size_t)row * SEQ + kv1 + lg * 8);
        }
    }
    __syncthreads();

    int buf = 0;
    for (int jt = jt0; jt < jt_end; ++jt) {
        // commit tile jt+1 (regs loaded a full iteration ago) into buf^1
        if (jt + 1 < jt_end) {
            #pragma unroll
            for (int s = 0; s < 2; ++s) {
                *(bf16x8*)((char*)Ks[buf ^ 1] + s * 4096 + tid * 16) = kr[s];
                *(bf16x8*)((char*)Vs[buf ^ 1] + s * 4096 + tid * 16) = vr[s];
            }
        }
        // issue loads for tile jt+2
        if (jt + 2 < jt_end) {
            const int kv2 = (jt + 2) * BN;
            #pragma unroll
            for (int s = 0; s < 2; ++s) {
                const int row = s * 32 + srow0;
                const int lg = sg ^ (row & 7);
                kr[s] = *(const bf16x8*)(kh + (size_t)(kv2 + row) * DH + lg * 8);
                vr[s] = *(const bf16x8*)(vh + (size_t)row * SEQ + kv2 + lg * 8);
            }
        }

        // ---- S^T = K * Q^T from buf: lane(li,g) reg r = S[q=qa+li][kv=t*16+g*4+r]
        const char* Kb = (const char*)Ks[buf];
        const char* Vb = (const char*)Vs[buf];
        float s4[2][4][4];                 // [a][t][r]
        #pragma unroll
        for (int t = 0; t < 4; ++t) {
            f32x4 sa0 = {}, sa1 = {};
            #pragma unroll
            for (int c = 0; c < 2; ++c) {
                bf16x8 kf = *(const bf16x8*)(Kb +
                    (t * 16 + li) * 128 + (((c * 4 + g) ^ (li & 7)) << 4));
                sa0 = __builtin_amdgcn_mfma_f32_16x16x32_bf16(kf, qf[0][c], sa0, 0, 0, 0);
                sa1 = __builtin_amdgcn_mfma_f32_16x16x32_bf16(kf, qf[1][c], sa1, 0, 0, 0);
            }
            #pragma unroll
            for (int r = 0; r < 4; ++r) { s4[0][t][r] = sa0[r]; s4[1][t][r] = sa1[r]; }
        }

        if (jt >= 2 * mt2) {               // diagonal region: causal mask
            #pragma unroll
            for (int a = 0; a < 2; ++a) {
                const int qr = q0 + w * 32 + a * 16 + li;
                #pragma unroll
                for (int t = 0; t < 4; ++t) {
                    #pragma unroll
                    for (int r = 0; r < 4; ++r)
                        if (jt * 64 + t * 16 + g * 4 + r > qr) s4[a][t][r] = -1e30f;
                }
            }
        }

        // ---- p = 2^s, packed bf16x4 in registers == A-frag for K=16 MFMA ----
        bf16x4 pf[2][4];
        #pragma unroll
        for (int a = 0; a < 2; ++a)
            #pragma unroll
            for (int t = 0; t < 4; ++t)
                #pragma unroll
                for (int r = 0; r < 4; ++r)
                    pf[a][t][r] = (__bf16)EXP2F(s4[a][t][r]);

        // ---- O += P V ; l += P * ones — all K=16 MFMAs, no LDS for P ----
        #pragma unroll
        for (int t = 0; t < 4; ++t) {
            accl[0] = mfma16_bf16(pf[0][t], ones4, accl[0]);
            accl[1] = mfma16_bf16(pf[1][t], ones4, accl[1]);
            #pragma unroll
            for (int nt = 0; nt < 4; ++nt) {
                // V B-frag: lane(li,g) j -> V[kv=t*16+g*4+j][d=nt*16+li]
                bf16x4 vf = *(const bf16x4*)(Vb + (nt * 16 + li) * 128 +
                    (((2 * t + (g >> 1)) ^ (li & 7)) << 4) + ((g & 1) << 3));
                acc[0][nt] = mfma16_bf16(pf[0][t], vf, acc[0][nt]);
                acc[1][nt] = mfma16_bf16(pf[1][t], vf, acc[1][nt]);
            }
        }

        if (jt + 1 < jt_end) __syncthreads();   // readers of buf done; buf^1 ready
        buf ^= 1;
    }

    // ---- partials out (O in bf16; l in f32) ----
    const int slot = (bh * 16 + mt2) * 4 + chunk;
    __bf16* po = opart + (size_t)slot * 8192;
    #pragma unroll
    for (int a = 0; a < 2; ++a) {
        #pragma unroll
        for (int r = 0; r < 4; ++r) {
            const int row = w * 32 + a * 16 + g * 4 + r;
            __bf16* op = po + row * 64 + li;
            #pragma unroll
            for (int t = 0; t < 4; ++t) op[t * 16] = (__bf16)acc[a][t][r];
            if (li == 0) lpart[(size_t)slot * 128 + row] = accl[a][r];
        }
    }
}

// ---------------- reduce: sum bf16 chunks, normalize ----------------
__global__ __launch_bounds__(256)
void fa_reduce(const __bf16* __restrict__ opart, const float* __restrict__ lpart,
               float* __restrict__ out)
{
    const int bx = blockIdx.x;             // 384 = bh*16 + mt2
    const int bh = bx >> 4, mt2 = bx & 15;
    const int nc = (mt2 >> 2) + 1;         // ceil((2*mt2+2)/8)
    const int base = (bh * 16 + mt2) * 4;
    const int tid = threadIdx.x;
    #pragma unroll
    for (int rnd = 0; rnd < 8; ++rnd) {
        const int flat = rnd * 1024 + tid * 4;
        const int row = flat >> 6;
        float o0 = 0, o1 = 0, o2 = 0, o3 = 0, l = 0;
        for (int c = 0; c < nc; ++c) {
            bf16x4 ov = *(const bf16x4*)(opart + (size_t)(base + c) * 8192 + flat);
            o0 += (float)ov[0]; o1 += (float)ov[1]; o2 += (float)ov[2]; o3 += (float)ov[3];
            l += lpart[(size_t)(base + c) * 128 + row];
        }
        const float inv = 1.0f / l;
        f32x4 res = { o0 * inv, o1 * inv, o2 * inv, o3 * inv };
        *(f32x4*)(out + (size_t)bh * SEQ * DH + (size_t)mt2 * 8192 + flat) = res;
    }
}

// ---------------- fallback: R1 self-contained kernel ----------------
__global__ __launch_bounds__(256, 2)
void fa_causal_kernel(const float* __restrict__ q, const float* __restrict__ k,
                      const float* __restrict__ v, float* __restrict__ out)
{
    const int mt = 31 - (blockIdx.x & 31);
    const int bh = blockIdx.x >> 5;
    const int tid = threadIdx.x;
    const int w = tid >> 6, lane = tid & 63;
    const int g = lane >> 4, li = lane & 15;
    const int m0 = mt * 64;
    __shared__ __bf16 KsF[BN][LDK];
    __shared__ __bf16 VsF[DH][LDK];
    __shared__ __bf16 PsF[4][16][LDK];
    const size_t head_off = (size_t)bh * SEQ * DH;
    const float* qh = q + head_off;
    const float* kh = k + head_off;
    const float* vh = v + head_off;
    float* oh = out + head_off;
    const int qrow = m0 + w * 16 + li;
    bf16x8 qf[2];
    {
        const float* qp = qh + (size_t)qrow * DH + g * 8;
        #pragma unroll
        for (int c = 0; c < 2; ++c) {
            const float* p = qp + c * 32;
            #pragma unroll
            for (int jj = 0; jj < 8; ++jj) qf[c][jj] = (__bf16)p[jj];
        }
    }
    f32x4 acc[4] = {};
    float mrow[4], lrow[4];
    #pragma unroll
    for (int r = 0; r < 4; ++r) { mrow[r] = -1e30f; lrow[r] = 0.0f; }
    const float scale = 0.125f;
    const int srow = tid >> 2, scol = (tid & 3) * 16;
    for (int jt = 0; jt <= mt; ++jt) {
        const int kv0 = jt * BN;
        __syncthreads();
        {
            const float* kp = kh + (size_t)(kv0 + srow) * DH + scol;
            __bf16 tmp[16];
            #pragma unroll
            for (int jj = 0; jj < 16; ++jj) tmp[jj] = (__bf16)kp[jj];
            *(bf16x8*)&KsF[srow][scol]     = *(bf16x8*)&tmp[0];
            *(bf16x8*)&KsF[srow][scol + 8] = *(bf16x8*)&tmp[8];
            const float* vp = vh + (size_t)(kv0 + srow) * DH + scol;
            #pragma unroll
            for (int jj = 0; jj < 16; ++jj) VsF[scol + jj][srow] = (__bf16)vp[jj];
        }
        __syncthreads();
        float s4[4][4];
        #pragma unroll
        for (int t = 0; t < 4; ++t) {
            f32x4 sa = {};
            #pragma unroll
            for (int c = 0; c < 2; ++c) {
                bf16x8 kfr = *(const bf16x8*)&KsF[t * 16 + li][c * 32 + g * 8];
                sa = __builtin_amdgcn_mfma_f32_16x16x32_bf16(qf[c], kfr, sa, 0, 0, 0);
            }
            #pragma unroll
            for (int r = 0; r < 4; ++r) s4[t][r] = sa[r] * scale;
        }
        if (jt == mt) {
            #pragma unroll
            for (int t = 0; t < 4; ++t) {
                const int col = kv0 + t * 16 + li;
                #pragma unroll
                for (int r = 0; r < 4; ++r)
                    if (col > m0 + w * 16 + g * 4 + r) s4[t][r] = -1e30f;
            }
        }
        #pragma unroll
        for (int r = 0; r < 4; ++r) {
            float mx = fmaxf(fmaxf(s4[0][r], s4[1][r]), fmaxf(s4[2][r], s4[3][r]));
            #pragma unroll
            for (int off = 1; off < 16; off <<= 1)
                mx = fmaxf(mx, __shfl_xor(mx, off, 64));
            const float mnew = fmaxf(mrow[r], mx);
            const float alpha = __expf(mrow[r] - mnew);
            mrow[r] = mnew;
            float ps = 0.0f;
            #pragma unroll
            for (int t = 0; t < 4; ++t) {
                const float p = __expf(s4[t][r] - mnew);
                s4[t][r] = p;
                ps += p;
            }
            #pragma unroll
            for (int off = 1; off < 16; off <<= 1)
                ps += __shfl_xor(ps, off, 64);
            lrow[r] = lrow[r] * alpha + ps;
            #pragma unroll
            for (int t = 0; t < 4; ++t) acc[t][r] *= alpha;
        }
        #pragma unroll
        for (int t = 0; t < 4; ++t)
            #pragma unroll
            for (int r = 0; r < 4; ++r)
                PsF[w][g * 4 + r][t * 16 + li] = (__bf16)s4[t][r];
        __syncthreads();
        #pragma unroll
        for (int c = 0; c < 2; ++c) {
            bf16x8 pf = *(const bf16x8*)&PsF[w][li][c * 32 + g * 8];
            #pragma unroll
            for (int t = 0; t < 4; ++t) {
                bf16x8 vfr = *(const bf16x8*)&VsF[t * 16 + li][c * 32 + g * 8];
                acc[t] = __builtin_amdgcn_mfma_f32_16x16x32_bf16(pf, vfr, acc[t], 0, 0, 0);
            }
        }
    }
    #pragma unroll
    for (int r = 0; r < 4; ++r) {
        const int row = m0 + w * 16 + g * 4 + r;
        const float inv = 1.0f / lrow[r];
        float* op = oh + (size_t)row * DH + li;
        #pragma unroll
        for (int t = 0; t < 4; ++t) op[t * 16] = acc[t][r] * inv;
    }
}

extern "C" void kernel_launch(void* const* d_in, const int* in_sizes, int n_in,
                              void* d_out, int out_size, void* d_ws, size_t ws_size,
                              hipStream_t stream) {
    (void)in_sizes; (void)n_in; (void)out_size;
    const float* q = (const float*)d_in[0];
    const float* k = (const float*)d_in[1];
    const float* v = (const float*)d_in[2];
    float* out = (float*)d_out;

    if (ws_size >= WS_FA7) {
        __bf16* qs = (__bf16*)d_ws;
        __bf16* ks = qs + ELEMS_PER_TENSOR;
        __bf16* vt = ks + ELEMS_PER_TENSOR;
        __bf16* opart = (__bf16*)((char*)d_ws + WS_BF16);
        float* lpart = (float*)((char*)d_ws + WS_BF16 + (size_t)NSLOT5 * 8192 * 2);
        prep_kernel<<<dim3(3072 + 768), dim3(256), 0, stream>>>(q, k, v, qs, ks, vt);
        fa8_kernel<<<dim3(NHEADS * 40), dim3(256), 0, stream>>>(qs, ks, vt, opart, lpart);
        fa_reduce<<<dim3(NHEADS * 16), dim3(256), 0, stream>>>(opart, lpart, out);
    } else {
        fa_causal_kernel<<<dim3(NHEADS * 32), dim3(256), 0, stream>>>(q, k, v, out);
    }
}

// Round 10
// 139.040 us; speedup vs baseline: 1.0608x; 1.0608x over previous
//
#include <hip/hip_runtime.h>
#include <hip/hip_bf16.h>

// Causal attention B=2,H=12,S=2048,D=64 fp32 in/out.
// R10 = fa7 (proven ~33us) + two levers:
//  1. Finer split-K: chunks of 4 k-tiles -> 72 (mt2,chunk)/head -> 1728
//     blocks, <=4 iters each (R7's 960 blocks at 3 blocks/CU LDS cap gave
//     only ~26% avg occupancy; finer grid keeps CUs full through the drain).
//  2. Q prepass dropped: Q rows are block-private -> fa reads f32 Q directly,
//     scales+packs to bf16 in the prologue. Prep = K convert + V transpose.
// R9 lesson (REVERTED): K=16 register-P PV costs 4x MFMA instructions for
// half-MAC shapes — LDS P round-trip at K=32 is cheaper. Keep fa7's PV.
// Carried: XCD swizzle (3 heads/XCD), double-buffered K/V + 1 barrier/iter,
// bf16 partial O + f32 l, BM=128, S^T=K*Q^T, static-max base-2 softmax,
// XOR-swizzled packed LDS (conflicts ~0).

#define SEQ 2048
#define DH 64
#define NHEADS 24
#define BN 64
#define LDK 72
#define ELEMS_PER_TENSOR (NHEADS * SEQ * DH)          // 3145728
#define NSLOT10 (NHEADS * 16 * 8)                     // 3072
#define WS_KV    ((size_t)2 * ELEMS_PER_TENSOR * 2)   // 12582912 B
#define WS_FA10  (WS_KV + (size_t)NSLOT10 * 8192 * 2 + (size_t)NSLOT10 * 128 * 4)

typedef float f32x4 __attribute__((ext_vector_type(4)));
typedef __bf16 bf16x8 __attribute__((ext_vector_type(8)));
typedef __bf16 bf16x4 __attribute__((ext_vector_type(4)));

#if __has_builtin(__builtin_amdgcn_exp2f)
#define EXP2F(x) __builtin_amdgcn_exp2f(x)
#else
#define EXP2F(x) exp2f(x)
#endif

#define QSCALE 0.1803368801111204f   // log2(e)/8: folds 1/sqrt(64) + base-2

// ---------------- pre-pass: K -> bf16, V -> bf16 transposed ----------------
__global__ __launch_bounds__(256)
void prep_kernel(const float* __restrict__ k, const float* __restrict__ v,
                 __bf16* __restrict__ ks, __bf16* __restrict__ vt)
{
    __shared__ __bf16 T[64][LDK];
    const int bx = blockIdx.x;
    const int tid = threadIdx.x;
    if (bx < 1536) {                       // K bf16 convert
        const int idx = (bx * 256 + tid) * 8;
        f32x4 a = *(const f32x4*)(k + idx);
        f32x4 b = *(const f32x4*)(k + idx + 4);
        bf16x8 o;
        #pragma unroll
        for (int j = 0; j < 4; ++j) { o[j] = (__bf16)a[j]; o[4 + j] = (__bf16)b[j]; }
        *(bf16x8*)(ks + idx) = o;
    } else {                               // V transpose to [bh][d][s]
        const int b2 = bx - 1536;
        const int bh = b2 >> 5;
        const int s0 = (b2 & 31) * 64;
        const int r = tid >> 2, c0 = (tid & 3) * 16;
        const float* vp = v + (size_t)bh * SEQ * DH + (size_t)(s0 + r) * DH + c0;
        __bf16 tmp[16];
        #pragma unroll
        for (int jj = 0; jj < 16; ++jj) tmp[jj] = (__bf16)vp[jj];
        *(bf16x8*)&T[r][c0]     = *(bf16x8*)&tmp[0];
        *(bf16x8*)&T[r][c0 + 8] = *(bf16x8*)&tmp[8];
        __syncthreads();
        const int d = tid >> 2, j0 = (tid & 3) * 16;
        __bf16 o[16];
        #pragma unroll
        for (int jj = 0; jj < 16; ++jj) o[jj] = T[j0 + jj][d];
        __bf16* op = vt + (size_t)bh * DH * SEQ + (size_t)d * SEQ + s0 + j0;
        *(bf16x8*)op       = *(bf16x8*)&o[0];
        *(bf16x8*)(op + 8) = *(bf16x8*)&o[8];
    }
}

// ---------------- main: BM=128, split-K(4), dbuf, XCD-swizzled ----------------
__global__ __launch_bounds__(256, 3)
void fa10_kernel(const float* __restrict__ q, const __bf16* __restrict__ ks,
                 const __bf16* __restrict__ vt,
                 __bf16* __restrict__ opart, float* __restrict__ lpart)
{
    const int bx = blockIdx.x;             // 1728 = 8 XCDs x 3 headgrp x 72
    const int xcd = bx & 7;
    const int sub = bx >> 3;               // 0..215
    const int bh = (sub / 72) * 8 + xcd;   // 3 heads pinned per XCD
    const int i = sub % 72;                // low i = high mt2 = heavy-first
    int mt2, ch;
    if      (i < 8)  { mt2 = 15; ch = i; }
    else if (i < 16) { mt2 = 14; ch = i - 8; }
    else if (i < 23) { mt2 = 13; ch = i - 16; }
    else if (i < 30) { mt2 = 12; ch = i - 23; }
    else if (i < 36) { mt2 = 11; ch = i - 30; }
    else if (i < 42) { mt2 = 10; ch = i - 36; }
    else if (i < 47) { mt2 = 9;  ch = i - 42; }
    else if (i < 52) { mt2 = 8;  ch = i - 47; }
    else if (i < 56) { mt2 = 7;  ch = i - 52; }
    else if (i < 60) { mt2 = 6;  ch = i - 56; }
    else if (i < 63) { mt2 = 5;  ch = i - 60; }
    else if (i < 66) { mt2 = 4;  ch = i - 63; }
    else if (i < 68) { mt2 = 3;  ch = i - 66; }
    else if (i < 70) { mt2 = 2;  ch = i - 68; }
    else if (i < 71) { mt2 = 1;  ch = 0; }
    else             { mt2 = 0;  ch = 0; }
    const int jt0 = ch * 4;
    const int jt_end = min(jt0 + 4, 2 * mt2 + 2);
    const int q0 = mt2 * 128;

    const int tid = threadIdx.x;
    const int w = tid >> 6, lane = tid & 63;
    const int g = lane >> 4, li = lane & 15;

    __shared__ __bf16 Ks[2][64 * 64];      // 16 KB double-buffered
    __shared__ __bf16 Vs[2][64 * 64];      // 16 KB
    __shared__ __bf16 Ps[4 * 32 * 64];     // 16 KB per-wave P tiles

    const __bf16* kh = ks + (size_t)bh * SEQ * DH;
    const __bf16* vh = vt + (size_t)bh * DH * SEQ;   // [d][s]

    // Q fragments: direct f32 load, scale+pack (B-operand layout for S^T)
    bf16x8 qf[2][2];
    #pragma unroll
    for (int a = 0; a < 2; ++a) {
        const float* qp = q + (size_t)bh * SEQ * DH +
                          (size_t)(q0 + w * 32 + a * 16 + li) * DH + g * 8;
        #pragma unroll
        for (int c = 0; c < 2; ++c) {
            f32x4 x0 = *(const f32x4*)(qp + c * 32);
            f32x4 x1 = *(const f32x4*)(qp + c * 32 + 4);
            #pragma unroll
            for (int j = 0; j < 4; ++j) {
                qf[a][c][j]     = (__bf16)(x0[j] * QSCALE);
                qf[a][c][4 + j] = (__bf16)(x1[j] * QSCALE);
            }
        }
    }

    bf16x8 ones;
    #pragma unroll
    for (int j = 0; j < 8; ++j) ones[j] = (__bf16)1.0f;

    f32x4 acc[2][4] = {};
    f32x4 accl[2] = {};

    const int srow0 = tid >> 3;            // staging: + s*32
    const int sg    = tid & 7;

    bf16x8 kr[2], vr[2];
    // ---- prologue: tile jt0 -> buf0; issue loads for jt0+1 ----
    #pragma unroll
    for (int s = 0; s < 2; ++s) {
        const int row = s * 32 + srow0;
        const int lg = sg ^ (row & 7);
        kr[s] = *(const bf16x8*)(kh + (size_t)(jt0 * BN + row) * DH + lg * 8);
        vr[s] = *(const bf16x8*)(vh + (size_t)row * SEQ + jt0 * BN + lg * 8);
    }
    #pragma unroll
    for (int s = 0; s < 2; ++s) {
        *(bf16x8*)((char*)Ks[0] + s * 4096 + tid * 16) = kr[s];
        *(bf16x8*)((char*)Vs[0] + s * 4096 + tid * 16) = vr[s];
    }
    if (jt0 + 1 < jt_end) {
        const int kv1 = (jt0 + 1) * BN;
        #pragma unroll
        for (int s = 0; s < 2; ++s) {
            const int row = s * 32 + srow0;
            const int lg = sg ^ (row & 7);
            kr[s] = *(const bf16x8*)(kh + (size_t)(kv1 + row) * DH + lg * 8);
            vr[s] = *(const bf16x8*)(vh + (size_t)row * SEQ + kv1 + lg * 8);
        }
    }
    __syncthreads();

    int buf = 0;
    for (int jt = jt0; jt < jt_end; ++jt) {
        // commit tile jt+1 (regs loaded a full iteration ago) into buf^1
        if (jt + 1 < jt_end) {
            #pragma unroll
            for (int s = 0; s < 2; ++s) {
                *(bf16x8*)((char*)Ks[buf ^ 1] + s * 4096 + tid * 16) = kr[s];
                *(bf16x8*)((char*)Vs[buf ^ 1] + s * 4096 + tid * 16) = vr[s];
            }
        }
        // issue loads for tile jt+2
        if (jt + 2 < jt_end) {
            const int kv2 = (jt + 2) * BN;
            #pragma unroll
            for (int s = 0; s < 2; ++s) {
                const int row = s * 32 + srow0;
                const int lg = sg ^ (row & 7);
                kr[s] = *(const bf16x8*)(kh + (size_t)(kv2 + row) * DH + lg * 8);
                vr[s] = *(const bf16x8*)(vh + (size_t)row * SEQ + kv2 + lg * 8);
            }
        }

        // ---- S^T = K * Q^T from buf ----
        const char* Kb = (const char*)Ks[buf];
        const char* Vb = (const char*)Vs[buf];
        float s4[2][4][4];                 // [a][t][r], kv = jt*64+t*16+g*4+r
        #pragma unroll
        for (int t = 0; t < 4; ++t) {
            f32x4 sa0 = {}, sa1 = {};
            #pragma unroll
            for (int c = 0; c < 2; ++c) {
                bf16x8 kf = *(const bf16x8*)(Kb +
                    (t * 16 + li) * 128 + (((c * 4 + g) ^ (li & 7)) << 4));
                sa0 = __builtin_amdgcn_mfma_f32_16x16x32_bf16(kf, qf[0][c], sa0, 0, 0, 0);
                sa1 = __builtin_amdgcn_mfma_f32_16x16x32_bf16(kf, qf[1][c], sa1, 0, 0, 0);
            }
            #pragma unroll
            for (int r = 0; r < 4; ++r) { s4[0][t][r] = sa0[r]; s4[1][t][r] = sa1[r]; }
        }

        if (jt >= 2 * mt2) {               // diagonal region: causal mask
            #pragma unroll
            for (int a = 0; a < 2; ++a) {
                const int qr = q0 + w * 32 + a * 16 + li;
                #pragma unroll
                for (int t = 0; t < 4; ++t) {
                    #pragma unroll
                    for (int r = 0; r < 4; ++r)
                        if (jt * 64 + t * 16 + g * 4 + r > qr) s4[a][t][r] = -1e30f;
                }
            }
        }

        // ---- p = 2^s -> packed b64 stores (4 consecutive kv per reg-quad) ----
        #pragma unroll
        for (int a = 0; a < 2; ++a) {
            const int row = a * 16 + li;
            #pragma unroll
            for (int t = 0; t < 4; ++t) {
                bf16x4 p4;
                #pragma unroll
                for (int r = 0; r < 4; ++r) p4[r] = (__bf16)EXP2F(s4[a][t][r]);
                const int pg = (t * 2 + (g >> 1)) ^ (li & 7);
                *(bf16x4*)((char*)Ps + w * 4096 + row * 128 + (pg << 4) + ((g & 1) << 3)) = p4;
            }
        }

        // ---- O += P V ; l += P * ones (pf as A-operand) ----
        #pragma unroll
        for (int c = 0; c < 2; ++c) {
            const int pgp = ((c * 4 + g) ^ (li & 7)) << 4;
            bf16x8 pf0 = *(const bf16x8*)((const char*)Ps + w * 4096 + li * 128 + pgp);
            bf16x8 pf1 = *(const bf16x8*)((const char*)Ps + w * 4096 + (16 + li) * 128 + pgp);
            accl[0] = __builtin_amdgcn_mfma_f32_16x16x32_bf16(pf0, ones, accl[0], 0, 0, 0);
            accl[1] = __builtin_amdgcn_mfma_f32_16x16x32_bf16(pf1, ones, accl[1], 0, 0, 0);
            #pragma unroll
            for (int t = 0; t < 4; ++t) {
                bf16x8 vf = *(const bf16x8*)(Vb + (t * 16 + li) * 128 + pgp);
                acc[0][t] = __builtin_amdgcn_mfma_f32_16x16x32_bf16(pf0, vf, acc[0][t], 0, 0, 0);
                acc[1][t] = __builtin_amdgcn_mfma_f32_16x16x32_bf16(pf1, vf, acc[1][t], 0, 0, 0);
            }
        }

        if (jt + 1 < jt_end) __syncthreads();   // readers of buf done; buf^1 ready
        buf ^= 1;
    }

    // ---- partials out (O in bf16; l in f32) ----
    const int slot = (bh * 16 + mt2) * 8 + ch;
    __bf16* po = opart + (size_t)slot * 8192;
    #pragma unroll
    for (int a = 0; a < 2; ++a) {
        #pragma unroll
        for (int r = 0; r < 4; ++r) {
            const int row = w * 32 + a * 16 + g * 4 + r;
            __bf16* op = po + row * 64 + li;
            #pragma unroll
            for (int t = 0; t < 4; ++t) op[t * 16] = (__bf16)acc[a][t][r];
            if (li == 0) lpart[(size_t)slot * 128 + row] = accl[a][r];
        }
    }
}

// ---------------- reduce: sum bf16 chunks, normalize ----------------
__global__ __launch_bounds__(256)
void fa_reduce(const __bf16* __restrict__ opart, const float* __restrict__ lpart,
               float* __restrict__ out)
{
    const int bx = blockIdx.x;             // 384 = bh*16 + mt2
    const int bh = bx >> 4, mt2 = bx & 15;
    const int nc = (mt2 + 2) >> 1;         // ceil((2*mt2+2)/4)
    const int base = (bh * 16 + mt2) * 8;
    const int tid = threadIdx.x;
    #pragma unroll
    for (int rnd = 0; rnd < 8; ++rnd) {
        const int flat = rnd * 1024 + tid * 4;
        const int row = flat >> 6;
        float o0 = 0, o1 = 0, o2 = 0, o3 = 0, l = 0;
        for (int c = 0; c < nc; ++c) {
            bf16x4 ov = *(const bf16x4*)(opart + (size_t)(base + c) * 8192 + flat);
            o0 += (float)ov[0]; o1 += (float)ov[1]; o2 += (float)ov[2]; o3 += (float)ov[3];
            l += lpart[(size_t)(base + c) * 128 + row];
        }
        const float inv = 1.0f / l;
        f32x4 res = { o0 * inv, o1 * inv, o2 * inv, o3 * inv };
        *(f32x4*)(out + (size_t)bh * SEQ * DH + (size_t)mt2 * 8192 + flat) = res;
    }
}

// ---------------- fallback: R1 self-contained kernel ----------------
__global__ __launch_bounds__(256, 2)
void fa_causal_kernel(const float* __restrict__ q, const float* __restrict__ k,
                      const float* __restrict__ v, float* __restrict__ out)
{
    const int mt = 31 - (blockIdx.x & 31);
    const int bh = blockIdx.x >> 5;
    const int tid = threadIdx.x;
    const int w = tid >> 6, lane = tid & 63;
    const int g = lane >> 4, li = lane & 15;
    const int m0 = mt * 64;
    __shared__ __bf16 KsF[BN][LDK];
    __shared__ __bf16 VsF[DH][LDK];
    __shared__ __bf16 PsF[4][16][LDK];
    const size_t head_off = (size_t)bh * SEQ * DH;
    const float* qh = q + head_off;
    const float* kh = k + head_off;
    const float* vh = v + head_off;
    float* oh = out + head_off;
    const int qrow = m0 + w * 16 + li;
    bf16x8 qf[2];
    {
        const float* qp = qh + (size_t)qrow * DH + g * 8;
        #pragma unroll
        for (int c = 0; c < 2; ++c) {
            const float* p = qp + c * 32;
            #pragma unroll
            for (int jj = 0; jj < 8; ++jj) qf[c][jj] = (__bf16)p[jj];
        }
    }
    f32x4 acc[4] = {};
    float mrow[4], lrow[4];
    #pragma unroll
    for (int r = 0; r < 4; ++r) { mrow[r] = -1e30f; lrow[r] = 0.0f; }
    const float scale = 0.125f;
    const int srow = tid >> 2, scol = (tid & 3) * 16;
    for (int jt = 0; jt <= mt; ++jt) {
        const int kv0 = jt * BN;
        __syncthreads();
        {
            const float* kp = kh + (size_t)(kv0 + srow) * DH + scol;
            __bf16 tmp[16];
            #pragma unroll
            for (int jj = 0; jj < 16; ++jj) tmp[jj] = (__bf16)kp[jj];
            *(bf16x8*)&KsF[srow][scol]     = *(bf16x8*)&tmp[0];
            *(bf16x8*)&KsF[srow][scol + 8] = *(bf16x8*)&tmp[8];
            const float* vp = vh + (size_t)(kv0 + srow) * DH + scol;
            #pragma unroll
            for (int jj = 0; jj < 16; ++jj) VsF[scol + jj][srow] = (__bf16)vp[jj];
        }
        __syncthreads();
        float s4[4][4];
        #pragma unroll
        for (int t = 0; t < 4; ++t) {
            f32x4 sa = {};
            #pragma unroll
            for (int c = 0; c < 2; ++c) {
                bf16x8 kfr = *(const bf16x8*)&KsF[t * 16 + li][c * 32 + g * 8];
                sa = __builtin_amdgcn_mfma_f32_16x16x32_bf16(qf[c], kfr, sa, 0, 0, 0);
            }
            #pragma unroll
            for (int r = 0; r < 4; ++r) s4[t][r] = sa[r] * scale;
        }
        if (jt == mt) {
            #pragma unroll
            for (int t = 0; t < 4; ++t) {
                const int col = kv0 + t * 16 + li;
                #pragma unroll
                for (int r = 0; r < 4; ++r)
                    if (col > m0 + w * 16 + g * 4 + r) s4[t][r] = -1e30f;
            }
        }
        #pragma unroll
        for (int r = 0; r < 4; ++r) {
            float mx = fmaxf(fmaxf(s4[0][r], s4[1][r]), fmaxf(s4[2][r], s4[3][r]));
            #pragma unroll
            for (int off = 1; off < 16; off <<= 1)
                mx = fmaxf(mx, __shfl_xor(mx, off, 64));
            const float mnew = fmaxf(mrow[r], mx);
            const float alpha = __expf(mrow[r] - mnew);
            mrow[r] = mnew;
            float ps = 0.0f;
            #pragma unroll
            for (int t = 0; t < 4; ++t) {
                const float p = __expf(s4[t][r] - mnew);
                s4[t][r] = p;
                ps += p;
            }
            #pragma unroll
            for (int off = 1; off < 16; off <<= 1)
                ps += __shfl_xor(ps, off, 64);
            lrow[r] = lrow[r] * alpha + ps;
            #pragma unroll
            for (int t = 0; t < 4; ++t) acc[t][r] *= alpha;
        }
        #pragma unroll
        for (int t = 0; t < 4; ++t)
            #pragma unroll
            for (int r = 0; r < 4; ++r)
                PsF[w][g * 4 + r][t * 16 + li] = (__bf16)s4[t][r];
        __syncthreads();
        #pragma unroll
        for (int c = 0; c < 2; ++c) {
            bf16x8 pf = *(const bf16x8*)&PsF[w][li][c * 32 + g * 8];
            #pragma unroll
            for (int t = 0; t < 4; ++t) {
                bf16x8 vfr = *(const bf16x8*)&VsF[t * 16 + li][c * 32 + g * 8];
                acc[t] = __builtin_amdgcn_mfma_f32_16x16x32_bf16(pf, vfr, acc[t], 0, 0, 0);
            }
        }
    }
    #pragma unroll
    for (int r = 0; r < 4; ++r) {
        const int row = m0 + w * 16 + g * 4 + r;
        const float inv = 1.0f / lrow[r];
        float* op = oh + (size_t)row * DH + li;
        #pragma unroll
        for (int t = 0; t < 4; ++t) op[t * 16] = acc[t][r] * inv;
    }
}

extern "C" void kernel_launch(void* const* d_in, const int* in_sizes, int n_in,
                              void* d_out, int out_size, void* d_ws, size_t ws_size,
                              hipStream_t stream) {
    (void)in_sizes; (void)n_in; (void)out_size;
    const float* q = (const float*)d_in[0];
    const float* k = (const float*)d_in[1];
    const float* v = (const float*)d_in[2];
    float* out = (float*)d_out;

    if (ws_size >= WS_FA10) {
        __bf16* ks = (__bf16*)d_ws;
        __bf16* vt = ks + ELEMS_PER_TENSOR;
        __bf16* opart = (__bf16*)((char*)d_ws + WS_KV);
        float* lpart = (float*)((char*)d_ws + WS_KV + (size_t)NSLOT10 * 8192 * 2);
        prep_kernel<<<dim3(1536 + 768), dim3(256), 0, stream>>>(k, v, ks, vt);
        fa10_kernel<<<dim3(1728), dim3(256), 0, stream>>>(q, ks, vt, opart, lpart);
        fa_reduce<<<dim3(NHEADS * 16), dim3(256), 0, stream>>>(opart, lpart, out);
    } else {
        fa_causal_kernel<<<dim3(NHEADS * 32), dim3(256), 0, stream>>>(q, k, v, out);
    }
}

// Round 11
// 131.100 us; speedup vs baseline: 1.1251x; 1.0606x over previous
//
#include <hip/hip_runtime.h>
#include <hip/hip_bf16.h>

// Causal attention B=2,H=12,S=2048,D=64 fp32 in/out.
// R11 = best-of composition after R10's decomposition:
//  - R7 split-K granularity (chunks of 8 k-tiles, 960 blocks, 1536 slots):
//    R10's chunk=4 doubled partials traffic (+~50MB) and prologue count for
//    no usable occupancy gain (LDS caps 3 blocks/CU) -> reverted.
//  - R10's Q-direct load (no Q prepass; prep = K convert + V transpose only).
//  - NEW: single-chunk q-tiles (mt2<=3) normalize in-register and write out
//    directly -> no partials for 96/384 (bh,mt2) pairs; reduce grid 288.
//  - NEW: reduce decodes bh=(r2/12)*8+(bx&7) so its blocks co-locate (round
//    robin heuristic) with the producer XCD's L2 copy of opart.
// Carried: XCD swizzle (3 heads/XCD), double-buffered K/V + 1 barrier/iter,
// bf16 partial O + f32 l, BM=128, S^T=K*Q^T (packed b64 P stores), static-max
// base-2 softmax, XOR-swizzled packed LDS (conflicts ~0).
// R9 lesson stands: K=16 register-P PV = 4x MFMA issue for half MACs; K=32
// LDS round-trip is cheaper.

#define SEQ 2048
#define DH 64
#define NHEADS 24
#define BN 64
#define LDK 72
#define ELEMS_PER_TENSOR (NHEADS * SEQ * DH)          // 3145728
#define NSLOT (NHEADS * 16 * 4)                       // 1536
#define WS_KV    ((size_t)2 * ELEMS_PER_TENSOR * 2)   // 12582912 B
#define WS_FA11  (WS_KV + (size_t)NSLOT * 8192 * 2 + (size_t)NSLOT * 128 * 4)

typedef float f32x4 __attribute__((ext_vector_type(4)));
typedef __bf16 bf16x8 __attribute__((ext_vector_type(8)));
typedef __bf16 bf16x4 __attribute__((ext_vector_type(4)));

#if __has_builtin(__builtin_amdgcn_exp2f)
#define EXP2F(x) __builtin_amdgcn_exp2f(x)
#else
#define EXP2F(x) exp2f(x)
#endif

#define QSCALE 0.1803368801111204f   // log2(e)/8: folds 1/sqrt(64) + base-2

// ---------------- pre-pass: K -> bf16, V -> bf16 transposed ----------------
__global__ __launch_bounds__(256)
void prep_kernel(const float* __restrict__ k, const float* __restrict__ v,
                 __bf16* __restrict__ ks, __bf16* __restrict__ vt)
{
    __shared__ __bf16 T[64][LDK];
    const int bx = blockIdx.x;
    const int tid = threadIdx.x;
    if (bx < 1536) {                       // K bf16 convert
        const int idx = (bx * 256 + tid) * 8;
        f32x4 a = *(const f32x4*)(k + idx);
        f32x4 b = *(const f32x4*)(k + idx + 4);
        bf16x8 o;
        #pragma unroll
        for (int j = 0; j < 4; ++j) { o[j] = (__bf16)a[j]; o[4 + j] = (__bf16)b[j]; }
        *(bf16x8*)(ks + idx) = o;
    } else {                               // V transpose to [bh][d][s]
        const int b2 = bx - 1536;
        const int bh = b2 >> 5;
        const int s0 = (b2 & 31) * 64;
        const int r = tid >> 2, c0 = (tid & 3) * 16;
        const float* vp = v + (size_t)bh * SEQ * DH + (size_t)(s0 + r) * DH + c0;
        __bf16 tmp[16];
        #pragma unroll
        for (int jj = 0; jj < 16; ++jj) tmp[jj] = (__bf16)vp[jj];
        *(bf16x8*)&T[r][c0]     = *(bf16x8*)&tmp[0];
        *(bf16x8*)&T[r][c0 + 8] = *(bf16x8*)&tmp[8];
        __syncthreads();
        const int d = tid >> 2, j0 = (tid & 3) * 16;
        __bf16 o[16];
        #pragma unroll
        for (int jj = 0; jj < 16; ++jj) o[jj] = T[j0 + jj][d];
        __bf16* op = vt + (size_t)bh * DH * SEQ + (size_t)d * SEQ + s0 + j0;
        *(bf16x8*)op       = *(bf16x8*)&o[0];
        *(bf16x8*)(op + 8) = *(bf16x8*)&o[8];
    }
}

// ---------------- main: BM=128, split-K(8), dbuf, XCD-swizzled ----------------
__global__ __launch_bounds__(256, 3)
void fa11_kernel(const float* __restrict__ q, const __bf16* __restrict__ ks,
                 const __bf16* __restrict__ vt,
                 __bf16* __restrict__ opart, float* __restrict__ lpart,
                 float* __restrict__ out)
{
    const int bx = blockIdx.x;             // 960 = 8 XCDs x 3 headgrp x 40
    const int xcd = bx & 7;
    const int sub = bx >> 3;               // 0..119
    const int bh = (sub / 40) * 8 + xcd;   // 3 heads pinned per XCD
    const int rem = 39 - (sub % 40);       // heavy-first within XCD
    int mt2, st;
    if      (rem >= 36) { mt2 = 15; st = 36; }
    else if (rem >= 32) { mt2 = 14; st = 32; }
    else if (rem >= 28) { mt2 = 13; st = 28; }
    else if (rem >= 24) { mt2 = 12; st = 24; }
    else if (rem >= 21) { mt2 = 11; st = 21; }
    else if (rem >= 18) { mt2 = 10; st = 18; }
    else if (rem >= 15) { mt2 = 9;  st = 15; }
    else if (rem >= 12) { mt2 = 8;  st = 12; }
    else if (rem >= 10) { mt2 = 7;  st = 10; }
    else if (rem >= 8)  { mt2 = 6;  st = 8; }
    else if (rem >= 6)  { mt2 = 5;  st = 6; }
    else if (rem >= 4)  { mt2 = 4;  st = 4; }
    else                { mt2 = rem; st = rem; }
    const int chunk = rem - st;
    const int jt0 = chunk * 8;
    const int jt_end = min(jt0 + 8, 2 * mt2 + 2);
    const int q0 = mt2 * 128;

    const int tid = threadIdx.x;
    const int w = tid >> 6, lane = tid & 63;
    const int g = lane >> 4, li = lane & 15;

    __shared__ __bf16 Ks[2][64 * 64];      // 16 KB double-buffered
    __shared__ __bf16 Vs[2][64 * 64];      // 16 KB
    __shared__ __bf16 Ps[4 * 32 * 64];     // 16 KB per-wave P tiles

    const __bf16* kh = ks + (size_t)bh * SEQ * DH;
    const __bf16* vh = vt + (size_t)bh * DH * SEQ;   // [d][s]

    // Q fragments: direct f32 load, scale+pack (B-operand layout for S^T)
    bf16x8 qf[2][2];
    #pragma unroll
    for (int a = 0; a < 2; ++a) {
        const float* qp = q + (size_t)bh * SEQ * DH +
                          (size_t)(q0 + w * 32 + a * 16 + li) * DH + g * 8;
        #pragma unroll
        for (int c = 0; c < 2; ++c) {
            f32x4 x0 = *(const f32x4*)(qp + c * 32);
            f32x4 x1 = *(const f32x4*)(qp + c * 32 + 4);
            #pragma unroll
            for (int j = 0; j < 4; ++j) {
                qf[a][c][j]     = (__bf16)(x0[j] * QSCALE);
                qf[a][c][4 + j] = (__bf16)(x1[j] * QSCALE);
            }
        }
    }

    bf16x8 ones;
    #pragma unroll
    for (int j = 0; j < 8; ++j) ones[j] = (__bf16)1.0f;

    f32x4 acc[2][4] = {};
    f32x4 accl[2] = {};

    const int srow0 = tid >> 3;            // staging: + s*32
    const int sg    = tid & 7;

    bf16x8 kr[2], vr[2];
    // ---- prologue: tile jt0 -> buf0; issue loads for jt0+1 ----
    #pragma unroll
    for (int s = 0; s < 2; ++s) {
        const int row = s * 32 + srow0;
        const int lg = sg ^ (row & 7);
        kr[s] = *(const bf16x8*)(kh + (size_t)(jt0 * BN + row) * DH + lg * 8);
        vr[s] = *(const bf16x8*)(vh + (size_t)row * SEQ + jt0 * BN + lg * 8);
    }
    #pragma unroll
    for (int s = 0; s < 2; ++s) {
        *(bf16x8*)((char*)Ks[0] + s * 4096 + tid * 16) = kr[s];
        *(bf16x8*)((char*)Vs[0] + s * 4096 + tid * 16) = vr[s];
    }
    if (jt0 + 1 < jt_end) {
        const int kv1 = (jt0 + 1) * BN;
        #pragma unroll
        for (int s = 0; s < 2; ++s) {
            const int row = s * 32 + srow0;
            const int lg = sg ^ (row & 7);
            kr[s] = *(const bf16x8*)(kh + (size_t)(kv1 + row) * DH + lg * 8);
            vr[s] = *(const bf16x8*)(vh + (size_t)row * SEQ + kv1 + lg * 8);
        }
    }
    __syncthreads();

    int buf = 0;
    for (int jt = jt0; jt < jt_end; ++jt) {
        // commit tile jt+1 (regs loaded a full iteration ago) into buf^1
        if (jt + 1 < jt_end) {
            #pragma unroll
            for (int s = 0; s < 2; ++s) {
                *(bf16x8*)((char*)Ks[buf ^ 1] + s * 4096 + tid * 16) = kr[s];
                *(bf16x8*)((char*)Vs[buf ^ 1] + s * 4096 + tid * 16) = vr[s];
            }
        }
        // issue loads for tile jt+2
        if (jt + 2 < jt_end) {
            const int kv2 = (jt + 2) * BN;
            #pragma unroll
            for (int s = 0; s < 2; ++s) {
                const int row = s * 32 + srow0;
                const int lg = sg ^ (row & 7);
                kr[s] = *(const bf16x8*)(kh + (size_t)(kv2 + row) * DH + lg * 8);
                vr[s] = *(const bf16x8*)(vh + (size_t)row * SEQ + kv2 + lg * 8);
            }
        }

        // ---- S^T = K * Q^T from buf ----
        const char* Kb = (const char*)Ks[buf];
        const char* Vb = (const char*)Vs[buf];
        float s4[2][4][4];                 // [a][t][r], kv = jt*64+t*16+g*4+r
        #pragma unroll
        for (int t = 0; t < 4; ++t) {
            f32x4 sa0 = {}, sa1 = {};
            #pragma unroll
            for (int c = 0; c < 2; ++c) {
                bf16x8 kf = *(const bf16x8*)(Kb +
                    (t * 16 + li) * 128 + (((c * 4 + g) ^ (li & 7)) << 4));
                sa0 = __builtin_amdgcn_mfma_f32_16x16x32_bf16(kf, qf[0][c], sa0, 0, 0, 0);
                sa1 = __builtin_amdgcn_mfma_f32_16x16x32_bf16(kf, qf[1][c], sa1, 0, 0, 0);
            }
            #pragma unroll
            for (int r = 0; r < 4; ++r) { s4[0][t][r] = sa0[r]; s4[1][t][r] = sa1[r]; }
        }

        if (jt >= 2 * mt2) {               // diagonal region: causal mask
            #pragma unroll
            for (int a = 0; a < 2; ++a) {
                const int qr = q0 + w * 32 + a * 16 + li;
                #pragma unroll
                for (int t = 0; t < 4; ++t) {
                    #pragma unroll
                    for (int r = 0; r < 4; ++r)
                        if (jt * 64 + t * 16 + g * 4 + r > qr) s4[a][t][r] = -1e30f;
                }
            }
        }

        // ---- p = 2^s -> packed b64 stores (4 consecutive kv per reg-quad) ----
        #pragma unroll
        for (int a = 0; a < 2; ++a) {
            const int row = a * 16 + li;
            #pragma unroll
            for (int t = 0; t < 4; ++t) {
                bf16x4 p4;
                #pragma unroll
                for (int r = 0; r < 4; ++r) p4[r] = (__bf16)EXP2F(s4[a][t][r]);
                const int pg = (t * 2 + (g >> 1)) ^ (li & 7);
                *(bf16x4*)((char*)Ps + w * 4096 + row * 128 + (pg << 4) + ((g & 1) << 3)) = p4;
            }
        }

        // ---- O += P V ; l += P * ones (pf as A-operand) ----
        #pragma unroll
        for (int c = 0; c < 2; ++c) {
            const int pgp = ((c * 4 + g) ^ (li & 7)) << 4;
            bf16x8 pf0 = *(const bf16x8*)((const char*)Ps + w * 4096 + li * 128 + pgp);
            bf16x8 pf1 = *(const bf16x8*)((const char*)Ps + w * 4096 + (16 + li) * 128 + pgp);
            accl[0] = __builtin_amdgcn_mfma_f32_16x16x32_bf16(pf0, ones, accl[0], 0, 0, 0);
            accl[1] = __builtin_amdgcn_mfma_f32_16x16x32_bf16(pf1, ones, accl[1], 0, 0, 0);
            #pragma unroll
            for (int t = 0; t < 4; ++t) {
                bf16x8 vf = *(const bf16x8*)(Vb + (t * 16 + li) * 128 + pgp);
                acc[0][t] = __builtin_amdgcn_mfma_f32_16x16x32_bf16(pf0, vf, acc[0][t], 0, 0, 0);
                acc[1][t] = __builtin_amdgcn_mfma_f32_16x16x32_bf16(pf1, vf, acc[1][t], 0, 0, 0);
            }
        }

        if (jt + 1 < jt_end) __syncthreads();   // readers of buf done; buf^1 ready
        buf ^= 1;
    }

    if (2 * mt2 + 2 <= 8) {
        // ---- single-chunk q-tile: normalize in-register, write out directly
        float* oh = out + (size_t)bh * SEQ * DH;
        #pragma unroll
        for (int a = 0; a < 2; ++a) {
            #pragma unroll
            for (int r = 0; r < 4; ++r) {
                const int row = q0 + w * 32 + a * 16 + g * 4 + r;
                const float inv = 1.0f / accl[a][r];
                float* op = oh + (size_t)row * DH + li;
                #pragma unroll
                for (int t = 0; t < 4; ++t) op[t * 16] = acc[a][t][r] * inv;
            }
        }
    } else {
        // ---- partials out (O in bf16; l in f32) ----
        const int slot = (bh * 16 + mt2) * 4 + chunk;
        __bf16* po = opart + (size_t)slot * 8192;
        #pragma unroll
        for (int a = 0; a < 2; ++a) {
            #pragma unroll
            for (int r = 0; r < 4; ++r) {
                const int row = w * 32 + a * 16 + g * 4 + r;
                __bf16* op = po + row * 64 + li;
                #pragma unroll
                for (int t = 0; t < 4; ++t) op[t * 16] = (__bf16)acc[a][t][r];
                if (li == 0) lpart[(size_t)slot * 128 + row] = accl[a][r];
            }
        }
    }
}

// ---------------- reduce: sum bf16 chunks, normalize (mt2 >= 4 only) ----------------
__global__ __launch_bounds__(256)
void fa_reduce(const __bf16* __restrict__ opart, const float* __restrict__ lpart,
               float* __restrict__ out)
{
    const int bx = blockIdx.x;             // 288 = 8 XCDs x 3 headgrp x 12
    const int xcd = bx & 7;
    const int r2 = bx >> 3;                // 0..35
    const int bh = (r2 / 12) * 8 + xcd;    // co-locate with producer XCD
    const int mt2 = 4 + (r2 % 12);
    const int nc = (mt2 >> 2) + 1;         // ceil((2*mt2+2)/8)
    const int base = (bh * 16 + mt2) * 4;
    const int tid = threadIdx.x;
    #pragma unroll
    for (int rnd = 0; rnd < 8; ++rnd) {
        const int flat = rnd * 1024 + tid * 4;
        const int row = flat >> 6;
        float o0 = 0, o1 = 0, o2 = 0, o3 = 0, l = 0;
        for (int c = 0; c < nc; ++c) {
            bf16x4 ov = *(const bf16x4*)(opart + (size_t)(base + c) * 8192 + flat);
            o0 += (float)ov[0]; o1 += (float)ov[1]; o2 += (float)ov[2]; o3 += (float)ov[3];
            l += lpart[(size_t)(base + c) * 128 + row];
        }
        const float inv = 1.0f / l;
        f32x4 res = { o0 * inv, o1 * inv, o2 * inv, o3 * inv };
        *(f32x4*)(out + (size_t)bh * SEQ * DH + (size_t)mt2 * 8192 + flat) = res;
    }
}

// ---------------- fallback: R1 self-contained kernel ----------------
__global__ __launch_bounds__(256, 2)
void fa_causal_kernel(const float* __restrict__ q, const float* __restrict__ k,
                      const float* __restrict__ v, float* __restrict__ out)
{
    const int mt = 31 - (blockIdx.x & 31);
    const int bh = blockIdx.x >> 5;
    const int tid = threadIdx.x;
    const int w = tid >> 6, lane = tid & 63;
    const int g = lane >> 4, li = lane & 15;
    const int m0 = mt * 64;
    __shared__ __bf16 KsF[BN][LDK];
    __shared__ __bf16 VsF[DH][LDK];
    __shared__ __bf16 PsF[4][16][LDK];
    const size_t head_off = (size_t)bh * SEQ * DH;
    const float* qh = q + head_off;
    const float* kh = k + head_off;
    const float* vh = v + head_off;
    float* oh = out + head_off;
    const int qrow = m0 + w * 16 + li;
    bf16x8 qf[2];
    {
        const float* qp = qh + (size_t)qrow * DH + g * 8;
        #pragma unroll
        for (int c = 0; c < 2; ++c) {
            const float* p = qp + c * 32;
            #pragma unroll
            for (int jj = 0; jj < 8; ++jj) qf[c][jj] = (__bf16)p[jj];
        }
    }
    f32x4 acc[4] = {};
    float mrow[4], lrow[4];
    #pragma unroll
    for (int r = 0; r < 4; ++r) { mrow[r] = -1e30f; lrow[r] = 0.0f; }
    const float scale = 0.125f;
    const int srow = tid >> 2, scol = (tid & 3) * 16;
    for (int jt = 0; jt <= mt; ++jt) {
        const int kv0 = jt * BN;
        __syncthreads();
        {
            const float* kp = kh + (size_t)(kv0 + srow) * DH + scol;
            __bf16 tmp[16];
            #pragma unroll
            for (int jj = 0; jj < 16; ++jj) tmp[jj] = (__bf16)kp[jj];
            *(bf16x8*)&KsF[srow][scol]     = *(bf16x8*)&tmp[0];
            *(bf16x8*)&KsF[srow][scol + 8] = *(bf16x8*)&tmp[8];
            const float* vp = vh + (size_t)(kv0 + srow) * DH + scol;
            #pragma unroll
            for (int jj = 0; jj < 16; ++jj) VsF[scol + jj][srow] = (__bf16)vp[jj];
        }
        __syncthreads();
        float s4[4][4];
        #pragma unroll
        for (int t = 0; t < 4; ++t) {
            f32x4 sa = {};
            #pragma unroll
            for (int c = 0; c < 2; ++c) {
                bf16x8 kfr = *(const bf16x8*)&KsF[t * 16 + li][c * 32 + g * 8];
                sa = __builtin_amdgcn_mfma_f32_16x16x32_bf16(qf[c], kfr, sa, 0, 0, 0);
            }
            #pragma unroll
            for (int r = 0; r < 4; ++r) s4[t][r] = sa[r] * scale;
        }
        if (jt == mt) {
            #pragma unroll
            for (int t = 0; t < 4; ++t) {
                const int col = kv0 + t * 16 + li;
                #pragma unroll
                for (int r = 0; r < 4; ++r)
                    if (col > m0 + w * 16 + g * 4 + r) s4[t][r] = -1e30f;
            }
        }
        #pragma unroll
        for (int r = 0; r < 4; ++r) {
            float mx = fmaxf(fmaxf(s4[0][r], s4[1][r]), fmaxf(s4[2][r], s4[3][r]));
            #pragma unroll
            for (int off = 1; off < 16; off <<= 1)
                mx = fmaxf(mx, __shfl_xor(mx, off, 64));
            const float mnew = fmaxf(mrow[r], mx);
            const float alpha = __expf(mrow[r] - mnew);
            mrow[r] = mnew;
            float ps = 0.0f;
            #pragma unroll
            for (int t = 0; t < 4; ++t) {
                const float p = __expf(s4[t][r] - mnew);
                s4[t][r] = p;
                ps += p;
            }
            #pragma unroll
            for (int off = 1; off < 16; off <<= 1)
                ps += __shfl_xor(ps, off, 64);
            lrow[r] = lrow[r] * alpha + ps;
            #pragma unroll
            for (int t = 0; t < 4; ++t) acc[t][r] *= alpha;
        }
        #pragma unroll
        for (int t = 0; t < 4; ++t)
            #pragma unroll
            for (int r = 0; r < 4; ++r)
                PsF[w][g * 4 + r][t * 16 + li] = (__bf16)s4[t][r];
        __syncthreads();
        #pragma unroll
        for (int c = 0; c < 2; ++c) {
            bf16x8 pf = *(const bf16x8*)&PsF[w][li][c * 32 + g * 8];
            #pragma unroll
            for (int t = 0; t < 4; ++t) {
                bf16x8 vfr = *(const bf16x8*)&VsF[t * 16 + li][c * 32 + g * 8];
                acc[t] = __builtin_amdgcn_mfma_f32_16x16x32_bf16(pf, vfr, acc[t], 0, 0, 0);
            }
        }
    }
    #pragma unroll
    for (int r = 0; r < 4; ++r) {
        const int row = m0 + w * 16 + g * 4 + r;
        const float inv = 1.0f / lrow[r];
        float* op = oh + (size_t)row * DH + li;
        #pragma unroll
        for (int t = 0; t < 4; ++t) op[t * 16] = acc[t][r] * inv;
    }
}

extern "C" void kernel_launch(void* const* d_in, const int* in_sizes, int n_in,
                              void* d_out, int out_size, void* d_ws, size_t ws_size,
                              hipStream_t stream) {
    (void)in_sizes; (void)n_in; (void)out_size;
    const float* q = (const float*)d_in[0];
    const float* k = (const float*)d_in[1];
    const float* v = (const float*)d_in[2];
    float* out = (float*)d_out;

    if (ws_size >= WS_FA11) {
        __bf16* ks = (__bf16*)d_ws;
        __bf16* vt = ks + ELEMS_PER_TENSOR;
        __bf16* opart = (__bf16*)((char*)d_ws + WS_KV);
        float* lpart = (float*)((char*)d_ws + WS_KV + (size_t)NSLOT * 8192 * 2);
        prep_kernel<<<dim3(1536 + 768), dim3(256), 0, stream>>>(k, v, ks, vt);
        fa11_kernel<<<dim3(960), dim3(256), 0, stream>>>(q, ks, vt, opart, lpart, out);
        fa_reduce<<<dim3(288), dim3(256), 0, stream>>>(opart, lpart, out);
    } else {
        fa_causal_kernel<<<dim3(NHEADS * 32), dim3(256), 0, stream>>>(q, k, v, out);
    }
}